// Round 11
// baseline (40.609 us; speedup 1.0000x reference)
//
#include <hip/hip_runtime.h>

#define N_PED  8192
#define HID    128
#define NN     36
#define IPB    8             // i-rows per block
#define SLICES 32            // j-slices per block (one per 8-thread group)
#define BLOCK  256           // IPB * SLICES
#define JS     256           // j's per thread (8192/32)
#define NB     1024          // 8192 / IPB
#define AWORDS (9 * BLOCK)   // words per array (9 bin-words, predicated inc)

// One quad = 4 pairs -> arrays A,B,C,D (distinct arrays => no in-quad aliasing).
// Reads A/B issue before C/D compute (latency overlap); single unambiguous
// s_waitcnt lgkmcnt(0) before the adds (R8 lesson: partial lgkmcnt counts
// cannot identify which op classes retired). Cross-quad same-array RAW is
// safe: write(quad n, X) is issued before read(quad n+1, X) and the per-wave
// LDS pipe executes same-address ops in issue order.
// Per pair: 15 VALU + 1 ds_read + 1 v_add + 1 ds_write.
__device__ __forceinline__ void quad4(
    float p0x, float p0y, float p1x, float p1y,
    float p2x, float p2y, float p3x, float p3y,
    float xi4, float yi4, unsigned vone,
    unsigned bA, unsigned bB, unsigned bC, unsigned bD)
{
    unsigned tA, tB, iA, aA, vA, iB, aB, vB, iC, aC, vC, iD, aD, vD;
    asm volatile(
        // ---- chains A,B front (interleaved for ILP)
        "v_sub_f32 %[tA], %[p0x], %[xi4]\n\t"
        "v_sub_f32 %[iA], %[p0y], %[yi4]\n\t"
        "v_sub_f32 %[tB], %[p1x], %[xi4]\n\t"
        "v_sub_f32 %[iB], %[p1y], %[yi4]\n\t"
        "v_cvt_i32_f32 %[tA], %[tA]\n\t"
        "v_cvt_i32_f32 %[iA], %[iA]\n\t"
        "v_cvt_i32_f32 %[tB], %[tB]\n\t"
        "v_cvt_i32_f32 %[iB], %[iB]\n\t"
        "v_add_u32 %[tA], -1, %[tA]\n\t"
        "v_add_u32 %[iA], -1, %[iA]\n\t"
        "v_add_u32 %[tB], -1, %[tB]\n\t"
        "v_add_u32 %[iB], -1, %[iB]\n\t"
        "v_max_u32 %[aA], %[tA], %[iA]\n\t"
        "v_max_u32 %[aB], %[tB], %[iB]\n\t"
        "v_mad_u32_u24 %[tA], %[tA], 6, %[iA]\n\t"   // binA
        "v_mad_u32_u24 %[tB], %[tB], 6, %[iB]\n\t"   // binB
        // ---- A back (vcc live region)
        "v_cmp_gt_u32 vcc, 6, %[aA]\n\t"
        "v_lshrrev_b32 %[aA], 2, %[tA]\n\t"
        "v_cndmask_b32 %[aA], 0, %[aA], vcc\n\t"     // wA (invalid -> word 0)
        "v_lshlrev_b32 %[iA], 3, %[tA]\n\t"
        "v_lshlrev_b32 %[iA], %[iA], %[one]\n\t"     // incA = 1<<((bin*8)&31)
        "v_cndmask_b32 %[iA], 0, %[iA], vcc\n\t"     // invalid -> +0
        "v_lshl_add_u32 %[aA], %[aA], 10, %[bA]\n\t" // addrA = baseA + w*1024
        // ---- B back
        "v_cmp_gt_u32 vcc, 6, %[aB]\n\t"
        "v_lshrrev_b32 %[aB], 2, %[tB]\n\t"
        "v_cndmask_b32 %[aB], 0, %[aB], vcc\n\t"
        "v_lshlrev_b32 %[iB], 3, %[tB]\n\t"
        "v_lshlrev_b32 %[iB], %[iB], %[one]\n\t"
        "v_cndmask_b32 %[iB], 0, %[iB], vcc\n\t"
        "v_lshl_add_u32 %[aB], %[aB], 10, %[bB]\n\t"
        // ---- issue A/B reads early: latency overlaps C/D compute
        "ds_read_b32 %[vA], %[aA]\n\t"
        "ds_read_b32 %[vB], %[aB]\n\t"
        // ---- chains C,D front
        "v_sub_f32 %[tA], %[p2x], %[xi4]\n\t"
        "v_sub_f32 %[iC], %[p2y], %[yi4]\n\t"
        "v_sub_f32 %[tB], %[p3x], %[xi4]\n\t"
        "v_sub_f32 %[iD], %[p3y], %[yi4]\n\t"
        "v_cvt_i32_f32 %[tA], %[tA]\n\t"
        "v_cvt_i32_f32 %[iC], %[iC]\n\t"
        "v_cvt_i32_f32 %[tB], %[tB]\n\t"
        "v_cvt_i32_f32 %[iD], %[iD]\n\t"
        "v_add_u32 %[tA], -1, %[tA]\n\t"
        "v_add_u32 %[iC], -1, %[iC]\n\t"
        "v_add_u32 %[tB], -1, %[tB]\n\t"
        "v_add_u32 %[iD], -1, %[iD]\n\t"
        "v_max_u32 %[aC], %[tA], %[iC]\n\t"
        "v_max_u32 %[aD], %[tB], %[iD]\n\t"
        "v_mad_u32_u24 %[tA], %[tA], 6, %[iC]\n\t"   // binC
        "v_mad_u32_u24 %[tB], %[tB], 6, %[iD]\n\t"   // binD
        // ---- C back
        "v_cmp_gt_u32 vcc, 6, %[aC]\n\t"
        "v_lshrrev_b32 %[aC], 2, %[tA]\n\t"
        "v_cndmask_b32 %[aC], 0, %[aC], vcc\n\t"
        "v_lshlrev_b32 %[iC], 3, %[tA]\n\t"
        "v_lshlrev_b32 %[iC], %[iC], %[one]\n\t"
        "v_cndmask_b32 %[iC], 0, %[iC], vcc\n\t"
        "v_lshl_add_u32 %[aC], %[aC], 10, %[bC]\n\t"
        // ---- D back
        "v_cmp_gt_u32 vcc, 6, %[aD]\n\t"
        "v_lshrrev_b32 %[aD], 2, %[tB]\n\t"
        "v_cndmask_b32 %[aD], 0, %[aD], vcc\n\t"
        "v_lshlrev_b32 %[iD], 3, %[tB]\n\t"
        "v_lshlrev_b32 %[iD], %[iD], %[one]\n\t"
        "v_cndmask_b32 %[iD], 0, %[iD], vcc\n\t"
        "v_lshl_add_u32 %[aD], %[aD], 10, %[bD]\n\t"
        "ds_read_b32 %[vC], %[aC]\n\t"
        "ds_read_b32 %[vD], %[aD]\n\t"
        // ---- one unambiguous drain, then finish all four RMWs
        "s_waitcnt lgkmcnt(0)\n\t"
        "v_add_u32 %[vA], %[vA], %[iA]\n\t"
        "v_add_u32 %[vB], %[vB], %[iB]\n\t"
        "v_add_u32 %[vC], %[vC], %[iC]\n\t"
        "v_add_u32 %[vD], %[vD], %[iD]\n\t"
        "ds_write_b32 %[aA], %[vA]\n\t"
        "ds_write_b32 %[aB], %[vB]\n\t"
        "ds_write_b32 %[aC], %[vC]\n\t"
        "ds_write_b32 %[aD], %[vD]\n\t"
        : [tA]"=&v"(tA), [tB]"=&v"(tB),
          [iA]"=&v"(iA), [aA]"=&v"(aA), [vA]"=&v"(vA),
          [iB]"=&v"(iB), [aB]"=&v"(aB), [vB]"=&v"(vB),
          [iC]"=&v"(iC), [aC]"=&v"(aC), [vC]"=&v"(vC),
          [iD]"=&v"(iD), [aD]"=&v"(aD), [vD]"=&v"(vD)
        : [p0x]"v"(p0x), [p0y]"v"(p0y), [p1x]"v"(p1x), [p1y]"v"(p1y),
          [p2x]"v"(p2x), [p2y]"v"(p2y), [p3x]"v"(p3x), [p3y]"v"(p3y),
          [xi4]"v"(xi4), [yi4]"v"(yi4), [one]"v"(vone),
          [bA]"v"(bA), [bB]"v"(bB), [bC]"v"(bC), [bD]"v"(bD)
        : "vcc");
}

__global__ __launch_bounds__(BLOCK, 4) void pool_kernel(
    const float* __restrict__ obs2_g,   // [8192][2]
    const float* __restrict__ Wg,       // [128][36] row-major
    const float* __restrict__ bias,     // [128]
    float* __restrict__ out)            // [8192][128]
{
    __shared__ unsigned s_h[4 * AWORDS];           // 36,864 B (arrays A..D)
    __shared__ float    s_rgrid[IPB][NN];          //  1,152 B
    __shared__ unsigned s_wsel[IPB];               //     32 B
    // 38,048 B -> 4 blocks/CU resident (16 waves/CU, 4 waves/SIMD); grid is
    // exactly 4 blocks of work per CU -> fully resident, no tail.

    const int tid = threadIdx.x;
    const int bid = blockIdx.x;

    // ---- Phase 0: zero all 4 arrays (bank-striped: bank = tid%32)
    #pragma unroll
    for (int k = 0; k < 36; ++k)
        s_h[tid + k * BLOCK] = 0u;

    // ---- per-thread row setup
    const int il    = tid & (IPB - 1);
    const int slice = tid >> 3;                    // 0..31
    const int i     = bid * IPB + il;

    const float2 pi = ((const float2*)obs2_g)[i];
    const float  xi4 = pi.x - 4.0f;
    const float  yi4 = pi.y - 4.0f;

    // self-pair bin via IDENTICAL arithmetic (handles fl(xi - fl(xi-4)) != 4)
    if (tid < IPB) {
        float dx = pi.x - xi4;
        float dy = pi.y - yi4;
        unsigned u1 = (unsigned)((int)dx) - 1u;
        unsigned u2 = (unsigned)((int)dy) - 1u;
        bool ok = (u1 < 6u) & (u2 < 6u);           // false iff NaN/inf row
        s_wsel[il] = ok ? (u1 * 6u + u2) : 255u;
    }
    __syncthreads();

    // ---- Phase 1: pairwise occupancy histogram (quad RMW, 4 arrays)
    const unsigned vone = 1u;
    const unsigned bA = (unsigned)(uintptr_t)&s_h[0 * AWORDS + tid];
    const unsigned bB = (unsigned)(uintptr_t)&s_h[1 * AWORDS + tid];
    const unsigned bC = (unsigned)(uintptr_t)&s_h[2 * AWORDS + tid];
    const unsigned bD = (unsigned)(uintptr_t)&s_h[3 * AWORDS + tid];

    #define PAIR8(r0, r1, r2, r3) do {                                   \
        quad4(r0.x, r0.y, r0.z, r0.w, r1.x, r1.y, r1.z, r1.w,            \
              xi4, yi4, vone, bA, bB, bC, bD);                           \
        quad4(r2.x, r2.y, r2.z, r2.w, r3.x, r3.y, r3.z, r3.w,            \
              xi4, yi4, vone, bA, bB, bC, bD);                           \
    } while (0)

    {
        const float4* jp = (const float4*)obs2_g + slice * (JS / 2);  // 128 float4
        float4 a0 = jp[0], a1 = jp[1], a2 = jp[2], a3 = jp[3];
        float4 b0 = jp[4], b1 = jp[5], b2 = jp[6], b3 = jp[7];
        jp += 8;
        #pragma unroll 1
        for (int it = 0; it < 15; ++it) {          // 15 x 16 + 16 = 256 pairs
            PAIR8(a0, a1, a2, a3);
            a0 = jp[0]; a1 = jp[1]; a2 = jp[2]; a3 = jp[3];
            PAIR8(b0, b1, b2, b3);
            b0 = jp[4]; b1 = jp[5]; b2 = jp[6]; b3 = jp[7];
            jp += 8;
        }
        PAIR8(a0, a1, a2, a3);
        PAIR8(b0, b1, b2, b3);
    }
    #undef PAIR8

    // asm DS ops are invisible to compiler waitcnt tracking: drain explicitly.
    asm volatile("s_waitcnt lgkmcnt(0)" ::: "memory");
    __syncthreads();

    // ---- Phase 2: byte-wise reduce over 32 slices x 4 arrays (72 tasks)
    if (tid < IPB * 9) {                           // 72
        const int ril = tid & (IPB - 1);
        const int w   = tid >> 3;                  // 0..8
        unsigned lo = 0u, hi = 0u;                 // 2x u16 lanes each (max 8192)
        #pragma unroll 4
        for (int sl = 0; sl < SLICES; ++sl) {
            unsigned t = (w << 8) + sl * IPB + ril;
            unsigned v0 = s_h[0 * AWORDS + t];
            unsigned v1 = s_h[1 * AWORDS + t];
            unsigned v2 = s_h[2 * AWORDS + t];
            unsigned v3 = s_h[3 * AWORDS + t];
            lo += (v0 & 0x00FF00FFu) + (v1 & 0x00FF00FFu)
                + (v2 & 0x00FF00FFu) + (v3 & 0x00FF00FFu);
            hi += ((v0 >> 8) & 0x00FF00FFu) + ((v1 >> 8) & 0x00FF00FFu)
                + ((v2 >> 8) & 0x00FF00FFu) + ((v3 >> 8) & 0x00FF00FFu);
        }
        unsigned s0 = lo & 0xFFFFu;
        unsigned s1 = hi & 0xFFFFu;
        unsigned s2 = lo >> 16;
        unsigned s3 = hi >> 16;
        const unsigned sel  = s_wsel[ril];
        const unsigned base = (unsigned)(w * 4);
        s0 -= (sel == base + 0u);
        s1 -= (sel == base + 1u);
        s2 -= (sel == base + 2u);
        s3 -= (sel == base + 3u);
        s_rgrid[ril][base + 0] = (float)s0;
        s_rgrid[ril][base + 1] = (float)s1;
        s_rgrid[ril][base + 2] = (float)s2;
        s_rgrid[ril][base + 3] = (float)s3;
    }
    __syncthreads();

    // ---- Phase 3: fused GEMM  out[i][h] = sum_k grid[i][k]*W[h][k] + b[h]
    const int h  = tid & (HID - 1);                // 0..127
    const int r0 = tid >> 7;                       // 0..1 (half-wave uniform)
    const float4* W4 = (const float4*)Wg;          // [128][9] float4

    const float bh = bias[h];
    float acc0 = bh, acc1 = bh, acc2 = bh, acc3 = bh;

    #pragma unroll
    for (int k4 = 0; k4 < 9; ++k4) {
        float4 w4 = W4[h * 9 + k4];
        float4 g0 = *(const float4*)&s_rgrid[r0    ][k4 * 4];
        float4 g1 = *(const float4*)&s_rgrid[r0 + 2][k4 * 4];
        float4 g2 = *(const float4*)&s_rgrid[r0 + 4][k4 * 4];
        float4 g3 = *(const float4*)&s_rgrid[r0 + 6][k4 * 4];
        acc0 += g0.x * w4.x + g0.y * w4.y + g0.z * w4.z + g0.w * w4.w;
        acc1 += g1.x * w4.x + g1.y * w4.y + g1.z * w4.z + g1.w * w4.w;
        acc2 += g2.x * w4.x + g2.y * w4.y + g2.z * w4.z + g2.w * w4.w;
        acc3 += g3.x * w4.x + g3.y * w4.y + g3.z * w4.z + g3.w * w4.w;
    }

    const int obase = bid * IPB;
    out[(obase + r0    ) * HID + h] = acc0;
    out[(obase + r0 + 2) * HID + h] = acc1;
    out[(obase + r0 + 4) * HID + h] = acc2;
    out[(obase + r0 + 6) * HID + h] = acc3;
}

extern "C" void kernel_launch(void* const* d_in, const int* in_sizes, int n_in,
                              void* d_out, int out_size, void* d_ws, size_t ws_size,
                              hipStream_t stream) {
    // inputs: 0=hidden_state (unused), 1=obs1 (unused), 2=obs2, 3=W, 4=b
    const float* obs2 = (const float*)d_in[2];
    const float* W    = (const float*)d_in[3];
    const float* b    = (const float*)d_in[4];
    float* out        = (float*)d_out;
    (void)in_sizes; (void)n_in; (void)out_size; (void)d_ws; (void)ws_size;

    hipLaunchKernelGGL(pool_kernel, dim3(NB), dim3(BLOCK), 0, stream,
                       obs2, W, b, out);
}